// Round 7
// baseline (260.795 us; speedup 1.0000x reference)
//
#include <hip/hip_runtime.h>
#include <cstdint>
#include <cstddef>

// ============================================================================
// ROUND 7: DIAGNOSTIC BUILD. Code identical to round 6 except k_gg0 is
// launched 3x (idempotent). Purpose: k_gg0 has never appeared in the top-5
// dispatch table (crowded out by ~60us harness fills), and two cost models
// disagree by 4x on its duration. Delta(dur_us) = 2 x gg0_warm, and the
// instances become directly visible if >=~61us. Decision tree in the round
// notes. No optimization claims this round.
// ============================================================================

#define NNODES 100000
#define FEATD  256
#define HIDD   256
#define NBATCH 512
#define FAN1   10            // hop-1 fanout
#define FAN2   25            // hop-2 fanout
#define NS1    (NBATCH*FAN1) // 5120
#define MTOT   (NBATCH+NS1)  // 5632

typedef __attribute__((ext_vector_type(8))) short short8;
typedef __attribute__((ext_vector_type(4))) float f32x4;

__device__ __forceinline__ unsigned short f2bf(float f) {
    unsigned int u = __float_as_uint(f);
    unsigned int r = (u + 0x7fffu + ((u >> 16) & 1u)) >> 16;
    return (unsigned short)r;
}
__device__ __forceinline__ float bf2f(unsigned short h) {
    return __uint_as_float(((unsigned int)h) << 16);
}

// ---------------- kernel 1: W convert+transpose  +  index precompute ----------------
__global__ __launch_bounds__(256) void k_prep(
    const float* __restrict__ Ws0, const float* __restrict__ Wn0,
    const float* __restrict__ Ws1, const float* __restrict__ Wn1,
    const int* __restrict__ adj, const int* __restrict__ batch,
    unsigned short* __restrict__ B0t, unsigned short* __restrict__ B1t,
    int* __restrict__ s1, int* __restrict__ s2) {
    const int t = threadIdx.x;
    if (blockIdx.x < 64) {
        __shared__ unsigned short Ts[64][72];
        const int which = blockIdx.x >> 5;
        const int loc   = blockIdx.x & 31;
        const int kt = loc >> 2, nt = loc & 3;
        const int k0 = kt * 64, n0 = nt * 64;
        const float* W;
        if (which == 0)
            W = (k0 < 256) ? (Ws0 + (size_t)k0 * 256) : (Wn0 + (size_t)(k0 - 256) * 256);
        else
            W = (k0 < 256) ? (Ws1 + (size_t)k0 * 256) : (Wn1 + (size_t)(k0 - 256) * 256);
        unsigned short* Bt = which ? B1t : B0t;
        #pragma unroll
        for (int i = 0; i < 4; ++i) {
            int s  = t + i * 256;
            int kr = s >> 4;
            int c4 = s & 15;
            float4 v = *reinterpret_cast<const float4*>(W + (size_t)kr * 256 + n0 + c4 * 4);
            Ts[c4 * 4 + 0][kr] = f2bf(v.x);
            Ts[c4 * 4 + 1][kr] = f2bf(v.y);
            Ts[c4 * 4 + 2][kr] = f2bf(v.z);
            Ts[c4 * 4 + 3][kr] = f2bf(v.w);
        }
        __syncthreads();
        #pragma unroll
        for (int i = 0; i < 2; ++i) {
            int s  = t + i * 256;
            int nl = s >> 3;
            int k8 = (s & 7) * 8;
            *reinterpret_cast<short8*>(Bt + (size_t)(n0 + nl) * 512 + k0 + k8) =
                *reinterpret_cast<const short8*>(&Ts[nl][k8]);
        }
        return;
    }
    // ---- index build: one block per batch element ----
    __shared__ int hs[FAN1];
    const int b  = blockIdx.x - 64;
    const int nb = batch[b];                       // uniform broadcast load
    if (t < FAN1) {
        int v = adj[(size_t)nb * FAN2 + t];
        s1[b * FAN1 + t] = v;
        hs[t] = v;
    }
    __syncthreads();
    if (t < FAN1 * FAN2) {                         // 250 threads
        const int u = t / FAN2, v = t - u * FAN2;
        s2[(size_t)(b * FAN1 + u) * FAN2 + v] = adj[(size_t)hs[u] * FAN2 + v];
    }
}

// Flat gather over a wave's 4 rows (round-6 structure, unchanged).
template<int FAN>
__device__ __forceinline__ void gather4(
    const float* __restrict__ feat, const int* nidx, const int* node,
    int l, int wv, unsigned short (*As)[520]) {
    static_assert(FAN % 5 == 0, "FAN must be a multiple of 5");
    constexpr int BPR = FAN / 5;     // 5-wide batches per row
    constexpr int NB4 = 4 * BPR;     // batches across the wave's 4 rows
    float4 sv0 = *reinterpret_cast<const float4*>(feat + (size_t)node[0] * FEATD + l * 4);
    float4 sv1 = *reinterpret_cast<const float4*>(feat + (size_t)node[1] * FEATD + l * 4);
    float4 sv2 = *reinterpret_cast<const float4*>(feat + (size_t)node[2] * FEATD + l * 4);
    float4 sv3 = *reinterpret_cast<const float4*>(feat + (size_t)node[3] * FEATD + l * 4);
#define GLD(ROW, K) (*reinterpret_cast<const float4*>( \
        feat + (size_t)__shfl(nidx[ROW], (K)) * FEATD + l * 4))
    float4 c0, c1, c2, c3, c4, n0, n1, n2, n3, n4;
    c0 = GLD(0, 0); c1 = GLD(0, 1); c2 = GLD(0, 2); c3 = GLD(0, 3); c4 = GLD(0, 4);
    float4 a = make_float4(0.f, 0.f, 0.f, 0.f);
    #pragma unroll
    for (int g = 0; g < NB4; ++g) {
        const int row = g / BPR;
        if (g + 1 < NB4) {
            const int nr = (g + 1) / BPR;
            const int nk = ((g + 1) % BPR) * 5;
            n0 = GLD(nr, nk + 0); n1 = GLD(nr, nk + 1); n2 = GLD(nr, nk + 2);
            n3 = GLD(nr, nk + 3); n4 = GLD(nr, nk + 4);
        }
        a.x += (c0.x + c1.x) + (c2.x + c3.x) + c4.x;
        a.y += (c0.y + c1.y) + (c2.y + c3.y) + c4.y;
        a.z += (c0.z + c1.z) + (c2.z + c3.z) + c4.z;
        a.w += (c0.w + c1.w) + (c2.w + c3.w) + c4.w;
        if ((g + 1) % BPR == 0) {
            const float s = 1.0f / (float)FAN;
            float4 sv = (row == 0) ? sv0 : (row == 1) ? sv1 : (row == 2) ? sv2 : sv3;
            ushort4 ps, pn;
            ps.x = f2bf(sv.x);      ps.y = f2bf(sv.y);
            ps.z = f2bf(sv.z);      ps.w = f2bf(sv.w);
            pn.x = f2bf(a.x * s);   pn.y = f2bf(a.y * s);
            pn.z = f2bf(a.z * s);   pn.w = f2bf(a.w * s);
            const int r = wv * 4 + row;
            *reinterpret_cast<ushort4*>(&As[r][l * 4])       = ps;
            *reinterpret_cast<ushort4*>(&As[r][256 + l * 4]) = pn;
            a = make_float4(0.f, 0.f, 0.f, 0.f);
        }
        if (g + 1 < NB4) { c0 = n0; c1 = n1; c2 = n2; c3 = n3; c4 = n4; }
    }
#undef GLD
}

// ---------------- kernel 2: gather + neighbor-mean + bf16 MFMA GEMM ----------------
// IDEMPOTENT: reads feat/batch/s1/s2/B0t, writes H0/H1 deterministically.
// Launched 3x this round (diagnostic).
__global__ __launch_bounds__(256) void k_gg0(
    const float* __restrict__ feat, const int* __restrict__ batch,
    const int* __restrict__ s1, const int* __restrict__ s2,
    const unsigned short* __restrict__ B0t,
    unsigned short* __restrict__ H0, unsigned short* __restrict__ H1) {
    __shared__ __align__(16) unsigned short As[16][520];
    const int t   = threadIdx.x;
    const int wv  = t >> 6;      // 0..3
    const int l   = t & 63;
    const int q   = l >> 4;
    const int m15 = l & 15;
    const int r0  = blockIdx.x * 16;
    const bool isBatch = (r0 < NBATCH);

    int node[4], nidx[4];
    #pragma unroll
    for (int i = 0; i < 4; ++i) {
        const int R = r0 + wv * 4 + i;
        if (isBatch) {
            node[i] = batch[R];
            nidx[i] = (l < FAN1) ? s1[R * FAN1 + l] : 0;
        } else {
            const int idx = R - NBATCH;
            node[i] = s1[idx];
            nidx[i] = (l < FAN2) ? s2[(size_t)idx * FAN2 + l] : 0;
        }
    }
    if (isBatch) gather4<FAN1>(feat, nidx, node, l, wv, As);
    else         gather4<FAN2>(feat, nidx, node, l, wv, As);
    __syncthreads();

    f32x4 acc0 = (f32x4)0.f, acc1 = (f32x4)0.f, acc2 = (f32x4)0.f, acc3 = (f32x4)0.f;
    const unsigned short* b0p = B0t + (size_t)(wv * 64 +  0 + m15) * 512;
    const unsigned short* b1p = B0t + (size_t)(wv * 64 + 16 + m15) * 512;
    const unsigned short* b2p = B0t + (size_t)(wv * 64 + 32 + m15) * 512;
    const unsigned short* b3p = B0t + (size_t)(wv * 64 + 48 + m15) * 512;
    #pragma unroll
    for (int kt = 0; kt < 16; ++kt) {
        const int kk = kt * 32 + q * 8;
        short8 a  = *reinterpret_cast<const short8*>(&As[m15][kk]);
        short8 b0 = *reinterpret_cast<const short8*>(b0p + kk);
        short8 b1 = *reinterpret_cast<const short8*>(b1p + kk);
        short8 b2 = *reinterpret_cast<const short8*>(b2p + kk);
        short8 b3 = *reinterpret_cast<const short8*>(b3p + kk);
        acc0 = __builtin_amdgcn_mfma_f32_16x16x32_bf16(a, b0, acc0, 0, 0, 0);
        acc1 = __builtin_amdgcn_mfma_f32_16x16x32_bf16(a, b1, acc1, 0, 0, 0);
        acc2 = __builtin_amdgcn_mfma_f32_16x16x32_bf16(a, b2, acc2, 0, 0, 0);
        acc3 = __builtin_amdgcn_mfma_f32_16x16x32_bf16(a, b3, acc3, 0, 0, 0);
    }

    #pragma unroll
    for (int f = 0; f < 4; ++f) {
        const int n = wv * 64 + f * 16 + m15;
        const f32x4& a = (f == 0) ? acc0 : (f == 1) ? acc1 : (f == 2) ? acc2 : acc3;
        #pragma unroll
        for (int j = 0; j < 4; ++j) {
            int m = r0 + q * 4 + j;
            unsigned short v = f2bf(fmaxf(a[j], 0.f));
            if (isBatch)
                H0[(size_t)m * HIDD + n] = v;
            else
                H1[(size_t)(m - NBATCH) * HIDD + n] = v;
        }
    }
}

// ---------------- kernel 3: layer-1 bf16 MFMA + H1 mean + L2 norm ----------------
__global__ __launch_bounds__(512) void k_l1(
    const unsigned short* __restrict__ H0, const unsigned short* __restrict__ H1,
    const unsigned short* __restrict__ B1t, float* __restrict__ out) {
    __shared__ __align__(16) unsigned short As[16][520];
    __shared__ float rn[16][8];
    const int t   = threadIdx.x;
    const int wv  = t >> 6;      // 0..7
    const int l   = t & 63;
    const int q   = l >> 4;
    const int m15 = l & 15;
    const int rb  = blockIdx.x * 16;

    {   // stage H0 half: 512 ushort8 slots, 1/thread
        int r = t >> 5, c8 = (t & 31) * 8;
        *reinterpret_cast<short8*>(&As[r][c8]) =
            *reinterpret_cast<const short8*>(H0 + (size_t)(rb + r) * HIDD + c8);
    }
    {   // stage mean(H1) half: 512 slots, each averages 10 bf16 rows in fp32
        int r = t >> 5, c8 = (t & 31) * 8;
        const unsigned short* base = H1 + (size_t)(rb + r) * FAN1 * HIDD + c8;
        float a[8];
        #pragma unroll
        for (int e = 0; e < 8; ++e) a[e] = 0.f;
        #pragma unroll
        for (int j = 0; j < FAN1; ++j) {
            short8 v = *reinterpret_cast<const short8*>(base + (size_t)j * HIDD);
            #pragma unroll
            for (int e = 0; e < 8; ++e) a[e] += bf2f((unsigned short)v[e]);
        }
        short8 p;
        #pragma unroll
        for (int e = 0; e < 8; ++e) p[e] = (short)f2bf(a[e] * (1.0f / FAN1));
        *reinterpret_cast<short8*>(&As[r][256 + c8]) = p;
    }
    __syncthreads();

    f32x4 acc0 = (f32x4)0.f, acc1 = (f32x4)0.f;
    const unsigned short* b0p = B1t + (size_t)(wv * 32 + m15) * 512;
    const unsigned short* b1p = B1t + (size_t)(wv * 32 + 16 + m15) * 512;
    #pragma unroll
    for (int kt = 0; kt < 8; ++kt) {
        const int kb = kt * 64;
        #pragma unroll
        for (int s2i = 0; s2i < 2; ++s2i) {
            const int kk = kb + s2i * 32 + q * 8;
            short8 a  = *reinterpret_cast<const short8*>(&As[m15][kk]);
            short8 b0 = *reinterpret_cast<const short8*>(b0p + kk);
            short8 b1 = *reinterpret_cast<const short8*>(b1p + kk);
            acc0 = __builtin_amdgcn_mfma_f32_16x16x32_bf16(a, b0, acc0, 0, 0, 0);
            acc1 = __builtin_amdgcn_mfma_f32_16x16x32_bf16(a, b1, acc1, 0, 0, 0);
        }
    }

    #pragma unroll
    for (int j = 0; j < 4; ++j) {
        float p = acc0[j] * acc0[j] + acc1[j] * acc1[j];
        p += __shfl_xor(p, 1);
        p += __shfl_xor(p, 2);
        p += __shfl_xor(p, 4);
        p += __shfl_xor(p, 8);
        if (m15 == 0) rn[q * 4 + j][wv] = p;
    }
    __syncthreads();

    #pragma unroll
    for (int j = 0; j < 4; ++j) {
        const int m = q * 4 + j;
        float s = rn[m][0] + rn[m][1] + rn[m][2] + rn[m][3]
                + rn[m][4] + rn[m][5] + rn[m][6] + rn[m][7];
        float inv = 1.0f / fmaxf(sqrtf(s), 1e-12f);
        out[(size_t)(rb + m) * HIDD + wv * 32 + m15]      = acc0[j] * inv;
        out[(size_t)(rb + m) * HIDD + wv * 32 + 16 + m15] = acc1[j] * inv;
    }
}

extern "C" void kernel_launch(void* const* d_in, const int* in_sizes, int n_in,
                              void* d_out, int out_size, void* d_ws, size_t ws_size,
                              hipStream_t stream) {
    const float* feat  = (const float*)d_in[0];
    const int*   adj   = (const int*)d_in[1];
    const int*   batch = (const int*)d_in[2];
    const float* Ws0   = (const float*)d_in[3];
    const float* Wn0   = (const float*)d_in[4];
    const float* Ws1   = (const float*)d_in[5];
    const float* Wn1   = (const float*)d_in[6];
    float* out = (float*)d_out;

    char* ws = (char*)d_ws;
    unsigned short* B0t = (unsigned short*)(ws + 0);
    unsigned short* B1t = (unsigned short*)(ws + 262144);
    unsigned short* H0  = (unsigned short*)(ws + 524288);
    unsigned short* H1  = (unsigned short*)(ws + 786432);
    int*            s1  = (int*)(ws + 3407872);
    int*            s2  = (int*)(ws + 3428352);

    k_prep<<<64 + NBATCH, 256, 0, stream>>>(Ws0, Wn0, Ws1, Wn1, adj, batch,
                                            B0t, B1t, s1, s2);
    // DIAGNOSTIC: 3x idempotent launches. Delta(dur_us) vs round 6 = 2x warm
    // k_gg0 duration; instances >=~61us become visible in the top-5 table.
    k_gg0<<<MTOT / 16, 256, 0, stream>>>(feat, batch, s1, s2, B0t, H0, H1);
    k_gg0<<<MTOT / 16, 256, 0, stream>>>(feat, batch, s1, s2, B0t, H0, H1);
    k_gg0<<<MTOT / 16, 256, 0, stream>>>(feat, batch, s1, s2, B0t, H0, H1);
    k_l1<<<NBATCH / 16, 512, 0, stream>>>(H0, H1, B1t, out);
}

// Round 8
// 195.959 us; speedup vs baseline: 1.3309x; 1.3309x over previous
//
#include <hip/hip_runtime.h>
#include <cstdint>
#include <cstddef>

#define NNODES 100000
#define FEATD  256
#define HIDD   256
#define NBATCH 512
#define FAN1   10            // hop-1 fanout
#define FAN2   25            // hop-2 fanout
#define NS1    (NBATCH*FAN1) // 5120
#define MTOT   (NBATCH+NS1)  // 5632

typedef __attribute__((ext_vector_type(8))) short short8;
typedef __attribute__((ext_vector_type(4))) float f32x4;

__device__ __forceinline__ unsigned short f2bf(float f) {
    unsigned int u = __float_as_uint(f);
    unsigned int r = (u + 0x7fffu + ((u >> 16) & 1u)) >> 16;
    return (unsigned short)r;
}
__device__ __forceinline__ float bf2f(unsigned short h) {
    return __uint_as_float(((unsigned int)h) << 16);
}

// ---------------- kernel 1: W convert+transpose  +  index precompute ----------------
// (unchanged from round 6)
__global__ __launch_bounds__(256) void k_prep(
    const float* __restrict__ Ws0, const float* __restrict__ Wn0,
    const float* __restrict__ Ws1, const float* __restrict__ Wn1,
    const int* __restrict__ adj, const int* __restrict__ batch,
    unsigned short* __restrict__ B0t, unsigned short* __restrict__ B1t,
    int* __restrict__ s1, int* __restrict__ s2) {
    const int t = threadIdx.x;
    if (blockIdx.x < 64) {
        __shared__ unsigned short Ts[64][72];
        const int which = blockIdx.x >> 5;
        const int loc   = blockIdx.x & 31;
        const int kt = loc >> 2, nt = loc & 3;
        const int k0 = kt * 64, n0 = nt * 64;
        const float* W;
        if (which == 0)
            W = (k0 < 256) ? (Ws0 + (size_t)k0 * 256) : (Wn0 + (size_t)(k0 - 256) * 256);
        else
            W = (k0 < 256) ? (Ws1 + (size_t)k0 * 256) : (Wn1 + (size_t)(k0 - 256) * 256);
        unsigned short* Bt = which ? B1t : B0t;
        #pragma unroll
        for (int i = 0; i < 4; ++i) {
            int s  = t + i * 256;
            int kr = s >> 4;
            int c4 = s & 15;
            float4 v = *reinterpret_cast<const float4*>(W + (size_t)kr * 256 + n0 + c4 * 4);
            Ts[c4 * 4 + 0][kr] = f2bf(v.x);
            Ts[c4 * 4 + 1][kr] = f2bf(v.y);
            Ts[c4 * 4 + 2][kr] = f2bf(v.z);
            Ts[c4 * 4 + 3][kr] = f2bf(v.w);
        }
        __syncthreads();
        #pragma unroll
        for (int i = 0; i < 2; ++i) {
            int s  = t + i * 256;
            int nl = s >> 3;
            int k8 = (s & 7) * 8;
            *reinterpret_cast<short8*>(Bt + (size_t)(n0 + nl) * 512 + k0 + k8) =
                *reinterpret_cast<const short8*>(&Ts[nl][k8]);
        }
        return;
    }
    __shared__ int hs[FAN1];
    const int b  = blockIdx.x - 64;
    const int nb = batch[b];
    if (t < FAN1) {
        int v = adj[(size_t)nb * FAN2 + t];
        s1[b * FAN1 + t] = v;
        hs[t] = v;
    }
    __syncthreads();
    if (t < FAN1 * FAN2) {
        const int u = t / FAN2, v = t - u * FAN2;
        s2[(size_t)(b * FAN1 + u) * FAN2 + v] = adj[(size_t)hs[u] * FAN2 + v];
    }
}

// Single-row gather: one wave owns one output row (r7 finding: per-CU random-row
// concurrency ~= 1 outstanding load per wave, so maximize WAVES, not per-wave
// ILP). 5-wide / 2-deep load pipeline, all temp indices compile-time.
template<int FAN>
__device__ __forceinline__ void gather_row(
    const float* __restrict__ feat, int nidx, int node,
    int l, int row, unsigned short (*As)[520]) {
    static_assert(FAN % 5 == 0, "FAN must be a multiple of 5");
    // self row issued first (FIFO: completes first, consumed last)
    float4 sv = *reinterpret_cast<const float4*>(feat + (size_t)node * FEATD + l * 4);
#define GLD(K) (*reinterpret_cast<const float4*>( \
        feat + (size_t)__shfl(nidx, (K)) * FEATD + l * 4))
    float4 c0, c1, c2, c3, c4, n0, n1, n2, n3, n4;
    c0 = GLD(0); c1 = GLD(1); c2 = GLD(2); c3 = GLD(3); c4 = GLD(4);
    float4 a = make_float4(0.f, 0.f, 0.f, 0.f);
    constexpr int NB = FAN / 5;
    #pragma unroll
    for (int g = 0; g < NB; ++g) {
        if (g + 1 < NB) {
            n0 = GLD(5*g+5); n1 = GLD(5*g+6); n2 = GLD(5*g+7);
            n3 = GLD(5*g+8); n4 = GLD(5*g+9);
        }
        a.x += (c0.x + c1.x) + (c2.x + c3.x) + c4.x;
        a.y += (c0.y + c1.y) + (c2.y + c3.y) + c4.y;
        a.z += (c0.z + c1.z) + (c2.z + c3.z) + c4.z;
        a.w += (c0.w + c1.w) + (c2.w + c3.w) + c4.w;
        if (g + 1 < NB) { c0 = n0; c1 = n1; c2 = n2; c3 = n3; c4 = n4; }
    }
#undef GLD
    const float s = 1.0f / (float)FAN;
    ushort4 ps, pn;
    ps.x = f2bf(sv.x);      ps.y = f2bf(sv.y);
    ps.z = f2bf(sv.z);      ps.w = f2bf(sv.w);
    pn.x = f2bf(a.x * s);   pn.y = f2bf(a.y * s);
    pn.z = f2bf(a.z * s);   pn.w = f2bf(a.w * s);
    *reinterpret_cast<ushort4*>(&As[row][l * 4])       = ps;
    *reinterpret_cast<ushort4*>(&As[row][256 + l * 4]) = pn;
}

// ---------------- kernel 2: gather + neighbor-mean + bf16 MFMA GEMM ----------------
// RESTRUCTURED FOR MAX TLP: 512 threads = 8 waves, ONE ROW PER WAVE, 8 rows per
// block, grid 704. __launch_bounds__(512,4) caps VGPR at 128 (gather needs ~80)
// => 2 blocks/CU resident = 16 waves/CU, ~3x round-6's 5.5. GEMM pads the 8-row
// tile to M=16 with zeroed LDS rows (MFMA is negligible: 1.5 GFLOP total);
// epilogue writes only the 8 real rows.
__global__ __launch_bounds__(512, 4) void k_gg0(
    const float* __restrict__ feat, const int* __restrict__ batch,
    const int* __restrict__ s1, const int* __restrict__ s2,
    const unsigned short* __restrict__ B0t,
    unsigned short* __restrict__ H0, unsigned short* __restrict__ H1) {
    __shared__ __align__(16) unsigned short As[16][520];
    const int t   = threadIdx.x;
    const int wv  = t >> 6;      // 0..7
    const int l   = t & 63;
    const int q   = l >> 4;
    const int m15 = l & 15;
    const int r0  = blockIdx.x * 8;
    const bool isBatch = (r0 < NBATCH);

    // zero the M-pad rows 8..15 over k range [0,512): 512 short8 chunks, 1/thread
    *reinterpret_cast<short8*>(&As[8 + wv][l * 8]) = (short8)0;

    // ---- Phase 1: each wave gathers its one row ----
    const int R = r0 + wv;
    int node, nidx;
    if (isBatch) {
        node = batch[R];                                   // uniform
        nidx = (l < FAN1) ? s1[R * FAN1 + l] : 0;          // coalesced
    } else {
        const int idx = R - NBATCH;
        node = s1[idx];                                    // uniform
        nidx = (l < FAN2) ? s2[(size_t)idx * FAN2 + l] : 0;
    }
    if (isBatch) gather_row<FAN1>(feat, nidx, node, l, wv, As);
    else         gather_row<FAN2>(feat, nidx, node, l, wv, As);
    __syncthreads();

    // ---- Phase 2: barrier-free MFMA K-loop; wave owns 32 cols (2 frags) ----
    f32x4 acc0 = (f32x4)0.f, acc1 = (f32x4)0.f;
    const unsigned short* b0p = B0t + (size_t)(wv * 32 +  0 + m15) * 512;
    const unsigned short* b1p = B0t + (size_t)(wv * 32 + 16 + m15) * 512;
    #pragma unroll
    for (int kt = 0; kt < 16; ++kt) {
        const int kk = kt * 32 + q * 8;
        short8 a  = *reinterpret_cast<const short8*>(&As[m15][kk]);
        short8 b0 = *reinterpret_cast<const short8*>(b0p + kk);
        short8 b1 = *reinterpret_cast<const short8*>(b1p + kk);
        acc0 = __builtin_amdgcn_mfma_f32_16x16x32_bf16(a, b0, acc0, 0, 0, 0);
        acc1 = __builtin_amdgcn_mfma_f32_16x16x32_bf16(a, b1, acc1, 0, 0, 0);
    }

    // ---- Epilogue: relu + bf16 write (only the 8 real rows) ----
    #pragma unroll
    for (int f = 0; f < 2; ++f) {
        const int n = wv * 32 + f * 16 + m15;
        const f32x4& a = f ? acc1 : acc0;
        #pragma unroll
        for (int j = 0; j < 4; ++j) {
            const int ml = q * 4 + j;
            if (ml < 8) {
                const int m = r0 + ml;
                unsigned short v = f2bf(fmaxf(a[j], 0.f));
                if (isBatch)
                    H0[(size_t)m * HIDD + n] = v;
                else
                    H1[(size_t)(m - NBATCH) * HIDD + n] = v;
            }
        }
    }
}

// ---------------- kernel 3: layer-1 bf16 MFMA + H1 mean + L2 norm ----------------
// (unchanged)
__global__ __launch_bounds__(512) void k_l1(
    const unsigned short* __restrict__ H0, const unsigned short* __restrict__ H1,
    const unsigned short* __restrict__ B1t, float* __restrict__ out) {
    __shared__ __align__(16) unsigned short As[16][520];
    __shared__ float rn[16][8];
    const int t   = threadIdx.x;
    const int wv  = t >> 6;      // 0..7
    const int l   = t & 63;
    const int q   = l >> 4;
    const int m15 = l & 15;
    const int rb  = blockIdx.x * 16;

    {   // stage H0 half: 512 ushort8 slots, 1/thread
        int r = t >> 5, c8 = (t & 31) * 8;
        *reinterpret_cast<short8*>(&As[r][c8]) =
            *reinterpret_cast<const short8*>(H0 + (size_t)(rb + r) * HIDD + c8);
    }
    {   // stage mean(H1) half: 512 slots, each averages 10 bf16 rows in fp32
        int r = t >> 5, c8 = (t & 31) * 8;
        const unsigned short* base = H1 + (size_t)(rb + r) * FAN1 * HIDD + c8;
        float a[8];
        #pragma unroll
        for (int e = 0; e < 8; ++e) a[e] = 0.f;
        #pragma unroll
        for (int j = 0; j < FAN1; ++j) {
            short8 v = *reinterpret_cast<const short8*>(base + (size_t)j * HIDD);
            #pragma unroll
            for (int e = 0; e < 8; ++e) a[e] += bf2f((unsigned short)v[e]);
        }
        short8 p;
        #pragma unroll
        for (int e = 0; e < 8; ++e) p[e] = (short)f2bf(a[e] * (1.0f / FAN1));
        *reinterpret_cast<short8*>(&As[r][256 + c8]) = p;
    }
    __syncthreads();

    f32x4 acc0 = (f32x4)0.f, acc1 = (f32x4)0.f;
    const unsigned short* b0p = B1t + (size_t)(wv * 32 + m15) * 512;
    const unsigned short* b1p = B1t + (size_t)(wv * 32 + 16 + m15) * 512;
    #pragma unroll
    for (int kt = 0; kt < 8; ++kt) {
        const int kb = kt * 64;
        #pragma unroll
        for (int s2i = 0; s2i < 2; ++s2i) {
            const int kk = kb + s2i * 32 + q * 8;
            short8 a  = *reinterpret_cast<const short8*>(&As[m15][kk]);
            short8 b0 = *reinterpret_cast<const short8*>(b0p + kk);
            short8 b1 = *reinterpret_cast<const short8*>(b1p + kk);
            acc0 = __builtin_amdgcn_mfma_f32_16x16x32_bf16(a, b0, acc0, 0, 0, 0);
            acc1 = __builtin_amdgcn_mfma_f32_16x16x32_bf16(a, b1, acc1, 0, 0, 0);
        }
    }

    #pragma unroll
    for (int j = 0; j < 4; ++j) {
        float p = acc0[j] * acc0[j] + acc1[j] * acc1[j];
        p += __shfl_xor(p, 1);
        p += __shfl_xor(p, 2);
        p += __shfl_xor(p, 4);
        p += __shfl_xor(p, 8);
        if (m15 == 0) rn[q * 4 + j][wv] = p;
    }
    __syncthreads();

    #pragma unroll
    for (int j = 0; j < 4; ++j) {
        const int m = q * 4 + j;
        float s = rn[m][0] + rn[m][1] + rn[m][2] + rn[m][3]
                + rn[m][4] + rn[m][5] + rn[m][6] + rn[m][7];
        float inv = 1.0f / fmaxf(sqrtf(s), 1e-12f);
        out[(size_t)(rb + m) * HIDD + wv * 32 + m15]      = acc0[j] * inv;
        out[(size_t)(rb + m) * HIDD + wv * 32 + 16 + m15] = acc1[j] * inv;
    }
}

extern "C" void kernel_launch(void* const* d_in, const int* in_sizes, int n_in,
                              void* d_out, int out_size, void* d_ws, size_t ws_size,
                              hipStream_t stream) {
    const float* feat  = (const float*)d_in[0];
    const int*   adj   = (const int*)d_in[1];
    const int*   batch = (const int*)d_in[2];
    const float* Ws0   = (const float*)d_in[3];
    const float* Wn0   = (const float*)d_in[4];
    const float* Ws1   = (const float*)d_in[5];
    const float* Wn1   = (const float*)d_in[6];
    float* out = (float*)d_out;

    // ws: B0t bf16 @0 (262144); B1t bf16 @262144 (262144);
    // H0 bf16 [512][256] @524288 (262144); H1 bf16 [5120][256] @786432 (2621440);
    // s1 int[5120] @3407872 (20480); s2 int[128000] @3428352 (512000).
    char* ws = (char*)d_ws;
    unsigned short* B0t = (unsigned short*)(ws + 0);
    unsigned short* B1t = (unsigned short*)(ws + 262144);
    unsigned short* H0  = (unsigned short*)(ws + 524288);
    unsigned short* H1  = (unsigned short*)(ws + 786432);
    int*            s1  = (int*)(ws + 3407872);
    int*            s2  = (int*)(ws + 3428352);

    k_prep<<<64 + NBATCH, 256, 0, stream>>>(Ws0, Wn0, Ws1, Wn1, adj, batch,
                                            B0t, B1t, s1, s2);
    k_gg0<<<MTOT / 8, 512, 0, stream>>>(feat, batch, s1, s2, B0t, H0, H1);
    k_l1<<<NBATCH / 16, 512, 0, stream>>>(H0, H1, B1t, out);
}